// Round 1
// baseline (788.833 us; speedup 1.0000x reference)
//
#include <hip/hip_runtime.h>

// PolynomialSketch: out[b,o] = (1/64)*exp(0.5*lv) * prod_k( sum_i x[b,i]*exp(-lls)*W[k,i,o] )
// B=16384, D_IN=1024, D_FEAT=4096, DEGREE=3

#define BATCH 16384
#define DIN   1024
#define DFEAT 4096

typedef short short8 __attribute__((ext_vector_type(8)));
typedef float f32x4  __attribute__((ext_vector_type(4)));

__device__ __forceinline__ unsigned short f2bf(float f) {
  unsigned int u = __float_as_uint(f);
  u += 0x7FFFu + ((u >> 16) & 1u);   // round-to-nearest-even
  return (unsigned short)(u >> 16);
}

// ---- prelude 1: xs_bf16[b,i] = bf16(x[b,i] * exp(-log_ls)) ----
__global__ void cast_x_kernel(const float4* __restrict__ x,
                              const float* __restrict__ log_ls,
                              ushort4* __restrict__ xs) {
  float inv = expf(-log_ls[0]);
  int i = blockIdx.x * 256 + threadIdx.x;
  float4 v = x[i];
  ushort4 o;
  o.x = f2bf(v.x * inv);
  o.y = f2bf(v.y * inv);
  o.z = f2bf(v.z * inv);
  o.w = f2bf(v.w * inv);
  xs[i] = o;
}

// ---- prelude 2: Wt[d, o, i] = bf16(W[d, i, o]) ----
__global__ void transpose_w_kernel(const float* __restrict__ W,
                                   unsigned short* __restrict__ Wt) {
  __shared__ float tile[32][33];
  int d  = blockIdx.z;
  int i0 = blockIdx.y * 32;   // d_in
  int o0 = blockIdx.x * 32;   // d_feat
  int tx = threadIdx.x, ty = threadIdx.y;
  const float* src = W + (size_t)d * DIN * DFEAT + (size_t)i0 * DFEAT + o0;
  for (int r = ty; r < 32; r += 8) tile[r][tx] = src[(size_t)r * DFEAT + tx];
  __syncthreads();
  unsigned short* dst = Wt + (size_t)d * DFEAT * DIN + (size_t)o0 * DIN + i0;
  for (int r = ty; r < 32; r += 8) dst[(size_t)r * DIN + tx] = f2bf(tile[tx][r]);
}

// ---- main fused kernel ----
// BM=128, BN=64, BK=64. 256 threads = 4 waves in 2x2; wave tile 64x32.
// 3 accumulator sets (one per degree), product fused in epilogue.
// LDS tiles stored as rows of 8 16B-chunks, chunk-XOR-swizzled: phys p = c ^ (row&7).
__global__ __launch_bounds__(256, 2) void sketch_gemm_kernel(
    const unsigned short* __restrict__ xs,   // [16384][1024] bf16 bits
    const unsigned short* __restrict__ Wt,   // [3][4096][1024] bf16 bits
    const float* __restrict__ log_var,
    float* __restrict__ out) {               // [16384][4096] fp32
  __shared__ unsigned short As[128 * 64];        // 16 KB
  __shared__ unsigned short Bs[3][64 * 64];      // 24 KB

  const int tid  = threadIdx.x;
  const int lane = tid & 63;
  const int w    = tid >> 6;
  const int wm   = w >> 1;        // wave row (0..1)
  const int wn   = w & 1;         // wave col (0..1)
  const int row  = lane & 15;
  const int quad = lane >> 4;

  // block swizzle: groups of 8 m-blocks x 64 n-blocks
  int bid = blockIdx.x;
  int grp = bid >> 9, rem = bid & 511;
  int bm = (grp << 3) + (rem & 7);   // 0..127
  int bn = rem >> 3;                 // 0..63

  f32x4 acc[3][4][2];
  #pragma unroll
  for (int d = 0; d < 3; ++d)
    #pragma unroll
    for (int mi = 0; mi < 4; ++mi)
      #pragma unroll
      for (int ni = 0; ni < 2; ++ni)
        acc[d][mi][ni] = (f32x4){0.f, 0.f, 0.f, 0.f};

  const unsigned short* xsrc = xs + (size_t)(bm * 128) * DIN;
  const unsigned short* wsrc = Wt + (size_t)(bn * 64) * DIN;

  for (int k0 = 0; k0 < DIN; k0 += 64) {
    __syncthreads();
    // stage A: 128 rows x 64 k (16 KB) = 4 wave-issues/wave
    #pragma unroll
    for (int j = 0; j < 4; ++j) {
      int gc = ((w * 4 + j) << 6) + lane;        // chunk id 0..1023
      int m  = gc >> 3;
      int c  = (gc & 7) ^ (m & 7);               // logical k-chunk
      __builtin_amdgcn_global_load_lds(
          (const __attribute__((address_space(1))) void*)(xsrc + (size_t)m * DIN + k0 + c * 8),
          (__attribute__((address_space(3))) void*)(As + ((w * 4 + j) << 9)),
          16, 0, 0);
    }
    // stage B (3 mats): 64 rows x 64 k each (8 KB) = 2 wave-issues/wave/mat
    #pragma unroll
    for (int mat = 0; mat < 3; ++mat) {
      #pragma unroll
      for (int j = 0; j < 2; ++j) {
        int gc = ((w * 2 + j) << 6) + lane;      // chunk id 0..511
        int n  = gc >> 3;
        int c  = (gc & 7) ^ (n & 7);
        __builtin_amdgcn_global_load_lds(
            (const __attribute__((address_space(1))) void*)(wsrc + (size_t)mat * (DFEAT * DIN) + (size_t)n * DIN + k0 + c * 8),
            (__attribute__((address_space(3))) void*)(Bs[mat] + ((w * 2 + j) << 9)),
            16, 0, 0);
      }
    }
    __syncthreads();

    #pragma unroll
    for (int kk = 0; kk < 64; kk += 32) {
      short8 a[4];
      #pragma unroll
      for (int mi = 0; mi < 4; ++mi) {
        int m = wm * 64 + mi * 16 + row;
        int p = ((kk >> 3) + quad) ^ (m & 7);
        a[mi] = *(const short8*)(As + m * 64 + p * 8);
      }
      short8 b[3][2];
      #pragma unroll
      for (int mat = 0; mat < 3; ++mat) {
        #pragma unroll
        for (int ni = 0; ni < 2; ++ni) {
          int n = wn * 32 + ni * 16 + row;
          int p = ((kk >> 3) + quad) ^ (n & 7);
          b[mat][ni] = *(const short8*)(Bs[mat] + n * 64 + p * 8);
        }
      }
      #pragma unroll
      for (int mat = 0; mat < 3; ++mat)
        #pragma unroll
        for (int mi = 0; mi < 4; ++mi)
          #pragma unroll
          for (int ni = 0; ni < 2; ++ni)
            acc[mat][mi][ni] = __builtin_amdgcn_mfma_f32_16x16x32_bf16(
                a[mi], b[mat][ni], acc[mat][mi][ni], 0, 0, 0);
    }
  }

  // epilogue: out = acc0*acc1*acc2 * (1/64)*exp(0.5*lv)
  float sc = 0.015625f * expf(0.5f * log_var[0]);
  #pragma unroll
  for (int mi = 0; mi < 4; ++mi) {
    #pragma unroll
    for (int ni = 0; ni < 2; ++ni) {
      int colg = bn * 64 + wn * 32 + ni * 16 + row;
      int rowg = bm * 128 + wm * 64 + mi * 16 + quad * 4;
      #pragma unroll
      for (int t = 0; t < 4; ++t) {
        float v = acc[0][mi][ni][t] * acc[1][mi][ni][t] * acc[2][mi][ni][t] * sc;
        out[(size_t)(rowg + t) * DFEAT + colg] = v;
      }
    }
  }
}

extern "C" void kernel_launch(void* const* d_in, const int* in_sizes, int n_in,
                              void* d_out, int out_size, void* d_ws, size_t ws_size,
                              hipStream_t stream) {
  const float* x   = (const float*)d_in[0];
  const float* W   = (const float*)d_in[1];
  const float* lls = (const float*)d_in[2];
  const float* lv  = (const float*)d_in[3];
  float* out = (float*)d_out;

  unsigned short* xs = (unsigned short*)d_ws;                       // 32 MiB
  unsigned short* Wt = xs + (size_t)BATCH * DIN;                    // 24 MiB

  cast_x_kernel<<<BATCH * DIN / 4 / 256, 256, 0, stream>>>(
      (const float4*)x, lls, (ushort4*)xs);

  transpose_w_kernel<<<dim3(DFEAT / 32, DIN / 32, 3), dim3(32, 8), 0, stream>>>(W, Wt);

  sketch_gemm_kernel<<<(BATCH / 128) * (DFEAT / 64), 256, 0, stream>>>(xs, Wt, lv, out);
}

// Round 2
// 628.601 us; speedup vs baseline: 1.2549x; 1.2549x over previous
//
#include <hip/hip_runtime.h>

// PolynomialSketch: out[b,o] = (1/64)*exp(0.5*lv) * prod_k( sum_i x[b,i]*exp(-lls)*W[k,i,o] )
// B=16384, D_IN=1024, D_FEAT=4096, DEGREE=3

#define BATCH 16384
#define DIN   1024
#define DFEAT 4096

typedef short short8 __attribute__((ext_vector_type(8)));
typedef float f32x4  __attribute__((ext_vector_type(4)));
typedef unsigned short ushort8v __attribute__((ext_vector_type(8)));

__device__ __forceinline__ unsigned short f2bf(float f) {
  unsigned int u = __float_as_uint(f);
  u += 0x7FFFu + ((u >> 16) & 1u);   // round-to-nearest-even
  return (unsigned short)(u >> 16);
}

// ---- prelude 1: xs_bf16[b,i] = bf16(x[b,i] * exp(-log_ls)) ----
// 8 floats/thread: 2x float4 load, 1x 16B store
__global__ void cast_x_kernel(const float4* __restrict__ x,
                              const float* __restrict__ log_ls,
                              ushort8v* __restrict__ xs) {
  float inv = expf(-log_ls[0]);
  int i = blockIdx.x * 256 + threadIdx.x;
  float4 v0 = x[i * 2];
  float4 v1 = x[i * 2 + 1];
  ushort8v o;
  o[0] = f2bf(v0.x * inv); o[1] = f2bf(v0.y * inv);
  o[2] = f2bf(v0.z * inv); o[3] = f2bf(v0.w * inv);
  o[4] = f2bf(v1.x * inv); o[5] = f2bf(v1.y * inv);
  o[6] = f2bf(v1.z * inv); o[7] = f2bf(v1.w * inv);
  xs[i] = o;
}

// ---- prelude 2: Wt[d, o, i] = bf16(W[d, i, o]) ----
// 32(i) x 64(o) tile; float4 global loads, ushort4 (8B) global stores.
// LDS pad 65: store-phase banks = (c + r + k) % 32, max 2-way (free per m136).
__global__ void transpose_w_kernel(const float* __restrict__ W,
                                   unsigned short* __restrict__ Wt) {
  __shared__ float tile[32][65];
  int d  = blockIdx.z;
  int i0 = blockIdx.y * 32;   // d_in
  int o0 = blockIdx.x * 64;   // d_feat
  int tid = threadIdx.x;      // 0..255
  const float* src = W + (size_t)d * DIN * DFEAT + (size_t)i0 * DFEAT + o0;
  #pragma unroll
  for (int j = 0; j < 2; ++j) {
    int idx = j * 256 + tid;       // 0..511
    int r = idx >> 4;              // i row 0..31
    int c = (idx & 15) * 4;        // o col
    float4 v = *(const float4*)(src + (size_t)r * DFEAT + c);
    tile[r][c + 0] = v.x; tile[r][c + 1] = v.y;
    tile[r][c + 2] = v.z; tile[r][c + 3] = v.w;
  }
  __syncthreads();
  unsigned short* dst = Wt + (size_t)d * DFEAT * DIN + (size_t)o0 * DIN + i0;
  #pragma unroll
  for (int j = 0; j < 2; ++j) {
    int idx = j * 256 + tid;
    int r = idx >> 3;              // o row 0..63
    int c = (idx & 7) * 4;         // i col
    ushort4 u;
    u.x = f2bf(tile[c + 0][r]);
    u.y = f2bf(tile[c + 1][r]);
    u.z = f2bf(tile[c + 2][r]);
    u.w = f2bf(tile[c + 3][r]);
    *(ushort4*)(dst + (size_t)r * DIN + c) = u;
  }
}

// ---- main fused kernel ----
// BM=128, BN=64, BK=64. 256 threads = 4 waves in 2x2; wave tile 64x32.
// 3 accumulator sets (one per degree), product fused in epilogue.
// LDS tiles stored as rows of 8 16B-chunks, chunk-XOR-swizzled: phys p = c ^ (row&7).
__global__ __launch_bounds__(256, 2) void sketch_gemm_kernel(
    const unsigned short* __restrict__ xs,   // [16384][1024] bf16 bits
    const unsigned short* __restrict__ Wt,   // [3][4096][1024] bf16 bits
    const float* __restrict__ log_var,
    float* __restrict__ out) {               // [16384][4096] fp32
  __shared__ unsigned short As[128 * 64];        // 16 KB
  __shared__ unsigned short Bs[3][64 * 64];      // 24 KB

  const int tid  = threadIdx.x;
  const int lane = tid & 63;
  const int w    = tid >> 6;
  const int wm   = w >> 1;        // wave row (0..1)
  const int wn   = w & 1;         // wave col (0..1)
  const int row  = lane & 15;
  const int quad = lane >> 4;

  // XCD-aware mapping: bid % 8 -> XCD (round-robin dispatch). Each XCD owns
  // a slice of 8 bn blocks (B slice = 3 MB, fits 4 MB per-XCD L2). Within an
  // XCD, 8 consecutive blocks share one bm (A tile reused from L2).
  int bid = blockIdx.x;
  int xcd = bid & 7;
  int t   = bid >> 3;                // 0..1023 per XCD
  int bn  = (xcd << 3) + (t & 7);    // 0..63
  int bm  = t >> 3;                  // 0..127

  f32x4 acc[3][4][2];
  #pragma unroll
  for (int d = 0; d < 3; ++d)
    #pragma unroll
    for (int mi = 0; mi < 4; ++mi)
      #pragma unroll
      for (int ni = 0; ni < 2; ++ni)
        acc[d][mi][ni] = (f32x4){0.f, 0.f, 0.f, 0.f};

  const unsigned short* xsrc = xs + (size_t)(bm * 128) * DIN;
  const unsigned short* wsrc = Wt + (size_t)(bn * 64) * DIN;

  for (int k0 = 0; k0 < DIN; k0 += 64) {
    __syncthreads();
    // stage A: 128 rows x 64 k (16 KB) = 4 wave-issues/wave
    #pragma unroll
    for (int j = 0; j < 4; ++j) {
      int gc = ((w * 4 + j) << 6) + lane;        // chunk id 0..1023
      int m  = gc >> 3;
      int c  = (gc & 7) ^ (m & 7);               // logical k-chunk
      __builtin_amdgcn_global_load_lds(
          (const __attribute__((address_space(1))) void*)(xsrc + (size_t)m * DIN + k0 + c * 8),
          (__attribute__((address_space(3))) void*)(As + ((w * 4 + j) << 9)),
          16, 0, 0);
    }
    // stage B (3 mats): 64 rows x 64 k each (8 KB) = 2 wave-issues/wave/mat
    #pragma unroll
    for (int mat = 0; mat < 3; ++mat) {
      #pragma unroll
      for (int j = 0; j < 2; ++j) {
        int gc = ((w * 2 + j) << 6) + lane;      // chunk id 0..511
        int n  = gc >> 3;
        int c  = (gc & 7) ^ (n & 7);
        __builtin_amdgcn_global_load_lds(
            (const __attribute__((address_space(1))) void*)(wsrc + (size_t)mat * (DFEAT * DIN) + (size_t)n * DIN + k0 + c * 8),
            (__attribute__((address_space(3))) void*)(Bs[mat] + ((w * 2 + j) << 9)),
            16, 0, 0);
      }
    }
    __syncthreads();

    #pragma unroll
    for (int kk = 0; kk < 64; kk += 32) {
      short8 a[4];
      #pragma unroll
      for (int mi = 0; mi < 4; ++mi) {
        int m = wm * 64 + mi * 16 + row;
        int p = ((kk >> 3) + quad) ^ (m & 7);
        a[mi] = *(const short8*)(As + m * 64 + p * 8);
      }
      short8 b[3][2];
      #pragma unroll
      for (int mat = 0; mat < 3; ++mat) {
        #pragma unroll
        for (int ni = 0; ni < 2; ++ni) {
          int n = wn * 32 + ni * 16 + row;
          int p = ((kk >> 3) + quad) ^ (n & 7);
          b[mat][ni] = *(const short8*)(Bs[mat] + n * 64 + p * 8);
        }
      }
      #pragma unroll
      for (int mat = 0; mat < 3; ++mat)
        #pragma unroll
        for (int mi = 0; mi < 4; ++mi)
          #pragma unroll
          for (int ni = 0; ni < 2; ++ni)
            acc[mat][mi][ni] = __builtin_amdgcn_mfma_f32_16x16x32_bf16(
                a[mi], b[mat][ni], acc[mat][mi][ni], 0, 0, 0);
    }
  }

  // epilogue: out = acc0*acc1*acc2 * (1/64)*exp(0.5*lv)
  float sc = 0.015625f * expf(0.5f * log_var[0]);
  #pragma unroll
  for (int mi = 0; mi < 4; ++mi) {
    #pragma unroll
    for (int ni = 0; ni < 2; ++ni) {
      int colg = bn * 64 + wn * 32 + ni * 16 + row;
      int rowg = bm * 128 + wm * 64 + mi * 16 + quad * 4;
      #pragma unroll
      for (int t2 = 0; t2 < 4; ++t2) {
        float v = acc[0][mi][ni][t2] * acc[1][mi][ni][t2] * acc[2][mi][ni][t2] * sc;
        out[(size_t)(rowg + t2) * DFEAT + colg] = v;
      }
    }
  }
}

extern "C" void kernel_launch(void* const* d_in, const int* in_sizes, int n_in,
                              void* d_out, int out_size, void* d_ws, size_t ws_size,
                              hipStream_t stream) {
  const float* x   = (const float*)d_in[0];
  const float* W   = (const float*)d_in[1];
  const float* lls = (const float*)d_in[2];
  const float* lv  = (const float*)d_in[3];
  float* out = (float*)d_out;

  unsigned short* xs = (unsigned short*)d_ws;                       // 32 MiB
  unsigned short* Wt = xs + (size_t)BATCH * DIN;                    // 24 MiB

  cast_x_kernel<<<BATCH * DIN / 8 / 256, 256, 0, stream>>>(
      (const float4*)x, lls, (ushort8v*)xs);

  transpose_w_kernel<<<dim3(DFEAT / 64, DIN / 32, 3), dim3(256), 0, stream>>>(W, Wt);

  sketch_gemm_kernel<<<(BATCH / 128) * (DFEAT / 64), 256, 0, stream>>>(xs, Wt, lv, out);
}